// Round 1
// baseline (279.777 us; speedup 1.0000x reference)
//
#include <hip/hip_runtime.h>

// ---- problem geometry ----
#define M_TOTAL 16384          // B*L
#define N_DIM   1024           // D (output/gate dim)
#define K_DIM   1024           // D (contraction)
#define L_SEQ   4096
#define B_SZ    4
#define D_DIM   1024
#define CH      128            // scan chunk length
#define NCHUNK  (L_SEQ / CH)   // 32
#define NCHAN   (B_SZ * D_DIM) // 4096

// ---- GEMM tile ----
#define BM 128
#define BN 128
#define BK 32
#define NK (K_DIM / BK)        // 32

typedef __attribute__((ext_vector_type(8))) short v8s;
typedef __attribute__((ext_vector_type(4))) float f32x4;

__device__ __forceinline__ ushort f2b(float f) {
  uint u = __float_as_uint(f);
  u += 0x7FFFu + ((u >> 16) & 1u);   // RNE to bf16 (inputs are finite)
  return (ushort)(u >> 16);
}
__device__ __forceinline__ float b2f(ushort u) {
  return __uint_as_float(((uint)u) << 16);
}

__global__ void cast_f32_bf16(const float* __restrict__ src, ushort* __restrict__ dst, int n4) {
  int i = blockIdx.x * blockDim.x + threadIdx.x;
  if (i >= n4) return;
  float4 v = reinterpret_cast<const float4*>(src)[i];
  ushort4 o = make_ushort4(f2b(v.x), f2b(v.y), f2b(v.z), f2b(v.w));
  reinterpret_cast<ushort4*>(dst)[i] = o;
}

// C[m,e] = sum_d X[m,d] * W[e,d]  (both operands K-contiguous, "B^T" layout)
// 128x128 tile, BK=32, 4 waves (each 64x64 via 4x4 16x16x32 MFMA), dbuf LDS via global_load_lds.
__launch_bounds__(256, 2)
__global__ void gemm3_bt(const ushort* __restrict__ X,
                         const ushort* __restrict__ W0, const ushort* __restrict__ W1,
                         const ushort* __restrict__ W2,
                         ushort* __restrict__ P0, ushort* __restrict__ P1, ushort* __restrict__ P2)
{
  __shared__ ushort lds[2][2][BM * BK];   // [buf][A|B][row*BK+k]  32 KiB

  const int z = blockIdx.z;
  const ushort* Wz = (z == 0) ? W0 : (z == 1) ? W1 : W2;
  ushort*       Pz = (z == 0) ? P0 : (z == 1) ? P1 : P2;

  const int n0 = blockIdx.x * BN;
  const int m0 = blockIdx.y * BM;
  const int tid  = threadIdx.x;
  const int lane = tid & 63;
  const int w    = tid >> 6;
  const int wr = w >> 1, wc = w & 1;
  const int fr = lane & 15, g = lane >> 4;

  // staging map: thread covers one 16B slot; tid*16B linear in tile (rows 0..63), part 1 -> rows 64..127
  const int srow = tid >> 2;          // 0..63
  const int scol = (tid & 3) * 8;     // bf16 elements within BK

  const ushort* Xbase = X  + (size_t)m0 * K_DIM;
  const ushort* Wbase = Wz + (size_t)n0 * K_DIM;

  int aoff[4], boff[4];
#pragma unroll
  for (int t = 0; t < 4; ++t) {
    aoff[t] = (wr * 64 + t * 16 + fr) * BK + g * 8;
    boff[t] = (wc * 64 + t * 16 + fr) * BK + g * 8;
  }

  f32x4 acc[4][4] = {};

  auto stage = [&](int buf, int kt) {
    const ushort* As = Xbase + (size_t)srow * K_DIM + kt * BK + scol;
    const ushort* Bs = Wbase + (size_t)srow * K_DIM + kt * BK + scol;
    ushort* la = &lds[buf][0][srow * BK + scol];
    ushort* lb = &lds[buf][1][srow * BK + scol];
#pragma unroll
    for (int p = 0; p < 2; ++p) {
      __builtin_amdgcn_global_load_lds(
          (const __attribute__((address_space(1))) void*)(As + (size_t)p * 64 * K_DIM),
          (__attribute__((address_space(3))) void*)(la + p * 64 * BK), 16, 0, 0);
      __builtin_amdgcn_global_load_lds(
          (const __attribute__((address_space(1))) void*)(Bs + (size_t)p * 64 * K_DIM),
          (__attribute__((address_space(3))) void*)(lb + p * 64 * BK), 16, 0, 0);
    }
  };

  stage(0, 0);
  __syncthreads();

  int buf = 0;
  for (int kt = 0; kt < NK; ++kt) {
    if (kt + 1 < NK) stage(buf ^ 1, kt + 1);
    v8s af[4], bw[4];
#pragma unroll
    for (int t = 0; t < 4; ++t) af[t] = *reinterpret_cast<const v8s*>(&lds[buf][0][aoff[t]]);
#pragma unroll
    for (int t = 0; t < 4; ++t) bw[t] = *reinterpret_cast<const v8s*>(&lds[buf][1][boff[t]]);
#pragma unroll
    for (int mi = 0; mi < 4; ++mi)
#pragma unroll
      for (int ni = 0; ni < 4; ++ni)
        acc[mi][ni] = __builtin_amdgcn_mfma_f32_16x16x32_bf16(af[mi], bw[ni], acc[mi][ni], 0, 0, 0);
    __syncthreads();
    buf ^= 1;
  }

  // epilogue: C/D layout col=lane&15, row=(lane>>4)*4+r  [m89-verified]
#pragma unroll
  for (int mi = 0; mi < 4; ++mi) {
#pragma unroll
    for (int ni = 0; ni < 4; ++ni) {
      const int col   = n0 + wc * 64 + ni * 16 + fr;
      const int rbase = m0 + wr * 64 + mi * 16 + g * 4;
#pragma unroll
      for (int r = 0; r < 4; ++r)
        Pz[(size_t)(rbase + r) * N_DIM + col] = f2b(acc[mi][ni][r]);
    }
  }
}

// gates: f = (1+e^-ip)/(2+e^-fp+e^-ip), i = 1-f, h~ = hp>=0 ? hp+0.5 : sigmoid(hp)
__device__ __forceinline__ void gates(float fp, float ip, float hp, float& a, float& v) {
  float Ef = __expf(-fp);
  float Ei = __expf(-ip);
  float r  = __builtin_amdgcn_rcpf(2.f + Ef + Ei);
  float f  = (1.f + Ei) * r;
  float i  = (1.f + Ef) * r;
  float ht = (hp >= 0.f) ? (hp + 0.5f) : __builtin_amdgcn_rcpf(1.f + __expf(-hp));
  a = f;
  v = i * ht;
}

// pass1: per (channel, chunk) compute aggregate h_end = A*h_start + V  (A=prod f, V=local scan from 0)
__global__ void scan_pass1(const ushort* __restrict__ Pf, const ushort* __restrict__ Pi,
                           const ushort* __restrict__ Ph,
                           const float* __restrict__ bfp, const float* __restrict__ bip,
                           const float* __restrict__ bhp,
                           float* __restrict__ AggA, float* __restrict__ AggV)
{
  int tid = blockIdx.x * blockDim.x + threadIdx.x;
  int c = tid & (NCHAN - 1);
  int chunk = tid >> 12;
  int d = c & (D_DIM - 1);
  int b = c >> 10;
  float vbf = bfp[d], vbi = bip[d], vbh = bhp[d];
  size_t base = ((size_t)b * L_SEQ + (size_t)chunk * CH) * D_DIM + d;
  float A = 1.f, V = 0.f;
#pragma unroll 4
  for (int t = 0; t < CH; ++t) {
    size_t idx = base + (size_t)t * D_DIM;
    float a, v;
    gates(b2f(Pf[idx]) + vbf, b2f(Pi[idx]) + vbi, b2f(Ph[idx]) + vbh, a, v);
    A *= a;
    V = fmaf(a, V, v);
  }
  AggA[chunk * NCHAN + c] = A;
  AggV[chunk * NCHAN + c] = V;
}

// mid: sequential combine across the 32 chunk aggregates per channel
__global__ void scan_mid(const float* __restrict__ AggA, const float* __restrict__ AggV,
                         float* __restrict__ Start)
{
  int c = blockIdx.x * blockDim.x + threadIdx.x;
  float h = 0.f;
#pragma unroll
  for (int j = 0; j < NCHUNK; ++j) {
    Start[j * NCHAN + c] = h;
    h = fmaf(AggA[j * NCHAN + c], h, AggV[j * NCHAN + c]);
  }
}

// pass2: replay each chunk with its true carry, write h directly (== exp(log_h))
__global__ void scan_pass2(const ushort* __restrict__ Pf, const ushort* __restrict__ Pi,
                           const ushort* __restrict__ Ph,
                           const float* __restrict__ bfp, const float* __restrict__ bip,
                           const float* __restrict__ bhp,
                           const float* __restrict__ Start, float* __restrict__ out)
{
  int tid = blockIdx.x * blockDim.x + threadIdx.x;
  int c = tid & (NCHAN - 1);
  int chunk = tid >> 12;
  int d = c & (D_DIM - 1);
  int b = c >> 10;
  float vbf = bfp[d], vbi = bip[d], vbh = bhp[d];
  size_t base = ((size_t)b * L_SEQ + (size_t)chunk * CH) * D_DIM + d;
  float h = Start[chunk * NCHAN + c];
#pragma unroll 4
  for (int t = 0; t < CH; ++t) {
    size_t idx = base + (size_t)t * D_DIM;
    float a, v;
    gates(b2f(Pf[idx]) + vbf, b2f(Pi[idx]) + vbi, b2f(Ph[idx]) + vbh, a, v);
    h = fmaf(a, h, v);
    out[idx] = h;
  }
}

extern "C" void kernel_launch(void* const* d_in, const int* in_sizes, int n_in,
                              void* d_out, int out_size, void* d_ws, size_t ws_size,
                              hipStream_t stream) {
  (void)in_sizes; (void)n_in; (void)out_size; (void)ws_size;
  const float* x  = (const float*)d_in[0];
  const float* Wf = (const float*)d_in[1];
  const float* bf = (const float*)d_in[2];
  const float* Wi = (const float*)d_in[3];
  const float* bi = (const float*)d_in[4];
  const float* Wh = (const float*)d_in[5];
  const float* bh = (const float*)d_in[6];
  float* out = (float*)d_out;

  // workspace layout (~142 MB total)
  ushort* xb  = (ushort*)d_ws;                         // 33.5 MB  x in bf16
  ushort* wfb = xb  + (size_t)M_TOTAL * K_DIM;         // 2 MB each
  ushort* wib = wfb + (size_t)N_DIM * K_DIM;
  ushort* whb = wib + (size_t)N_DIM * K_DIM;
  ushort* Pf  = whb + (size_t)N_DIM * K_DIM;           // 33.5 MB each, bf16 preacts
  ushort* Pi  = Pf  + (size_t)M_TOTAL * N_DIM;
  ushort* Ph  = Pi  + (size_t)M_TOTAL * N_DIM;
  float* AggA  = (float*)(Ph + (size_t)M_TOTAL * N_DIM);
  float* AggV  = AggA + NCHAN * NCHUNK;
  float* Start = AggV + NCHAN * NCHUNK;

  cast_f32_bf16<<<(M_TOTAL * K_DIM / 4) / 256, 256, 0, stream>>>(x,  xb,  M_TOTAL * K_DIM / 4);
  cast_f32_bf16<<<(N_DIM  * K_DIM / 4) / 256, 256, 0, stream>>>(Wf, wfb, N_DIM * K_DIM / 4);
  cast_f32_bf16<<<(N_DIM  * K_DIM / 4) / 256, 256, 0, stream>>>(Wi, wib, N_DIM * K_DIM / 4);
  cast_f32_bf16<<<(N_DIM  * K_DIM / 4) / 256, 256, 0, stream>>>(Wh, whb, N_DIM * K_DIM / 4);

  gemm3_bt<<<dim3(N_DIM / BN, M_TOTAL / BM, 3), 256, 0, stream>>>(xb, wfb, wib, whb, Pf, Pi, Ph);

  scan_pass1<<<(NCHAN * NCHUNK) / 256, 256, 0, stream>>>(Pf, Pi, Ph, bf, bi, bh, AggA, AggV);
  scan_mid<<<NCHAN / 256, 256, 0, stream>>>(AggA, AggV, Start);
  scan_pass2<<<(NCHAN * NCHUNK) / 256, 256, 0, stream>>>(Pf, Pi, Ph, bf, bi, bh, Start, out);
}

// Round 2
// 212.086 us; speedup vs baseline: 1.3192x; 1.3192x over previous
//
#include <hip/hip_runtime.h>

// ---- problem geometry ----
#define M_TOTAL 16384          // B*L
#define N_DIM   1024           // D
#define K_DIM   1024
#define L_SEQ   4096
#define B_SZ    4
#define D_DIM   1024
#define CH      64             // scan chunk length
#define NCHUNK  (L_SEQ / CH)   // 64
#define NCHAN   (B_SZ * D_DIM) // 4096

// ---- GEMM tile ----
#define BM 128
#define BN 128
#define BK 32
#define NK (K_DIM / BK)        // 32
#define TPB 512                // 8 waves, 4x2 wave grid (wave tile 32x64)

typedef __attribute__((ext_vector_type(8))) short v8s;
typedef __attribute__((ext_vector_type(4))) float f32x4;

__device__ __forceinline__ ushort f2b(float f) {
  uint u = __float_as_uint(f);
  u += 0x7FFFu + ((u >> 16) & 1u);   // RNE (finite inputs)
  return (ushort)(u >> 16);
}
__device__ __forceinline__ float b2f(ushort u) {
  return __uint_as_float(((uint)u) << 16);
}

__global__ void cast_f32_bf16(const float* __restrict__ src, ushort* __restrict__ dst, int n4) {
  int i = blockIdx.x * blockDim.x + threadIdx.x;
  if (i >= n4) return;
  float4 v = reinterpret_cast<const float4*>(src)[i];
  ushort4 o = make_ushort4(f2b(v.x), f2b(v.y), f2b(v.z), f2b(v.w));
  reinterpret_cast<ushort4*>(dst)[i] = o;
}

// gates: f = (1+e^-ip)/(2+e^-fp+e^-ip), i = 1-f, h~ = hp>=0 ? hp+0.5 : sigmoid(hp)
__device__ __forceinline__ void gates(float fp, float ip, float hp, float& a, float& v) {
  float Ef = __expf(-fp);
  float Ei = __expf(-ip);
  float r  = __builtin_amdgcn_rcpf(2.f + Ef + Ei);
  float f  = (1.f + Ei) * r;
  float i  = (1.f + Ef) * r;
  float ht = (hp >= 0.f) ? (hp + 0.5f) : __builtin_amdgcn_rcpf(1.f + __expf(-hp));
  a = f;
  v = i * ht;
}

// Fused 3-GEMM: one block computes the 128x128 tile of f,i,h preacts (shared X stage),
// epilogue computes gates and writes packed (a,v) bf16 pairs.
__launch_bounds__(TPB, 4)
__global__ void gemm_fused(const ushort* __restrict__ X,
                           const ushort* __restrict__ W0, const ushort* __restrict__ W1,
                           const ushort* __restrict__ W2,
                           const float* __restrict__ bfp, const float* __restrict__ bip,
                           const float* __restrict__ bhp,
                           uint* __restrict__ Pav)
{
  __shared__ ushort lds[2][4][BM * BK];   // [buf][A,Bf,Bi,Bh][row*BK+k]  64 KiB

  const int n0 = blockIdx.x * BN;
  const int m0 = blockIdx.y * BM;
  const int tid  = threadIdx.x;
  const int lane = tid & 63;
  const int w    = tid >> 6;          // 0..7
  const int wr = w >> 1;              // 0..3 (32-row strip)
  const int wc = w & 1;               // 0..1 (64-col strip)
  const int fr = lane & 15, g = lane >> 4;

  // staging: thread -> one 16B slot; halfword index = tid*8 == row*BK + c8
  const int srow = tid >> 2;          // 0..127
  const int scol = (tid & 3) * 8;

  const ushort* Arow = X  + (size_t)(m0 + srow) * K_DIM + scol;
  const ushort* Brow0 = W0 + (size_t)(n0 + srow) * K_DIM + scol;
  const ushort* Brow1 = W1 + (size_t)(n0 + srow) * K_DIM + scol;
  const ushort* Brow2 = W2 + (size_t)(n0 + srow) * K_DIM + scol;

  int aoff[2], boff[4];
#pragma unroll
  for (int t = 0; t < 2; ++t) aoff[t] = (wr * 32 + t * 16 + fr) * BK + g * 8;
#pragma unroll
  for (int t = 0; t < 4; ++t) boff[t] = (wc * 64 + t * 16 + fr) * BK + g * 8;

  f32x4 acc[3][2][4] = {};

  auto stage = [&](int buf, int kt) {
    const int ko = kt * BK;
    __builtin_amdgcn_global_load_lds(
        (const __attribute__((address_space(1))) void*)(Arow + ko),
        (__attribute__((address_space(3))) void*)(&lds[buf][0][tid * 8]), 16, 0, 0);
    __builtin_amdgcn_global_load_lds(
        (const __attribute__((address_space(1))) void*)(Brow0 + ko),
        (__attribute__((address_space(3))) void*)(&lds[buf][1][tid * 8]), 16, 0, 0);
    __builtin_amdgcn_global_load_lds(
        (const __attribute__((address_space(1))) void*)(Brow1 + ko),
        (__attribute__((address_space(3))) void*)(&lds[buf][2][tid * 8]), 16, 0, 0);
    __builtin_amdgcn_global_load_lds(
        (const __attribute__((address_space(1))) void*)(Brow2 + ko),
        (__attribute__((address_space(3))) void*)(&lds[buf][3][tid * 8]), 16, 0, 0);
  };

  stage(0, 0);
  __syncthreads();

  int buf = 0;
  for (int kt = 0; kt < NK; ++kt) {
    if (kt + 1 < NK) stage(buf ^ 1, kt + 1);
    v8s af[2];
#pragma unroll
    for (int t = 0; t < 2; ++t) af[t] = *reinterpret_cast<const v8s*>(&lds[buf][0][aoff[t]]);
#pragma unroll
    for (int z = 0; z < 3; ++z) {
      v8s b0 = *reinterpret_cast<const v8s*>(&lds[buf][1 + z][boff[0]]);
      v8s b1 = *reinterpret_cast<const v8s*>(&lds[buf][1 + z][boff[1]]);
      v8s b2 = *reinterpret_cast<const v8s*>(&lds[buf][1 + z][boff[2]]);
      v8s b3 = *reinterpret_cast<const v8s*>(&lds[buf][1 + z][boff[3]]);
#pragma unroll
      for (int mi = 0; mi < 2; ++mi) {
        acc[z][mi][0] = __builtin_amdgcn_mfma_f32_16x16x32_bf16(af[mi], b0, acc[z][mi][0], 0, 0, 0);
        acc[z][mi][1] = __builtin_amdgcn_mfma_f32_16x16x32_bf16(af[mi], b1, acc[z][mi][1], 0, 0, 0);
        acc[z][mi][2] = __builtin_amdgcn_mfma_f32_16x16x32_bf16(af[mi], b2, acc[z][mi][2], 0, 0, 0);
        acc[z][mi][3] = __builtin_amdgcn_mfma_f32_16x16x32_bf16(af[mi], b3, acc[z][mi][3], 0, 0, 0);
      }
    }
    __syncthreads();
    buf ^= 1;
  }

  // epilogue: C/D layout col=lane&15, row=(lane>>4)*4+r  [m89-verified]
#pragma unroll
  for (int ni = 0; ni < 4; ++ni) {
    const int col = n0 + wc * 64 + ni * 16 + fr;
    const float vbf = bfp[col], vbi = bip[col], vbh = bhp[col];
#pragma unroll
    for (int mi = 0; mi < 2; ++mi) {
      const int row0 = m0 + wr * 32 + mi * 16 + g * 4;
#pragma unroll
      for (int r = 0; r < 4; ++r) {
        float a, v;
        gates(acc[0][mi][ni][r] + vbf, acc[1][mi][ni][r] + vbi, acc[2][mi][ni][r] + vbh, a, v);
        Pav[(size_t)(row0 + r) * N_DIM + col] = (uint)f2b(a) | ((uint)f2b(v) << 16);
      }
    }
  }
}

// pass1: per (channel, chunk) aggregate: h_end = A*h_start + V
__global__ void scan_pass1(const uint* __restrict__ Pav,
                           float* __restrict__ AggA, float* __restrict__ AggV)
{
  int tid = blockIdx.x * blockDim.x + threadIdx.x;
  int c = tid & (NCHAN - 1);
  int chunk = tid >> 12;
  int d = c & (D_DIM - 1);
  int b = c >> 10;
  size_t base = ((size_t)b * L_SEQ + (size_t)chunk * CH) * D_DIM + d;
  float A = 1.f, V = 0.f;
#pragma unroll 4
  for (int t = 0; t < CH; ++t) {
    uint u = Pav[base + (size_t)t * D_DIM];
    float a = b2f((ushort)(u & 0xFFFFu));
    float v = b2f((ushort)(u >> 16));
    A *= a;
    V = fmaf(a, V, v);
  }
  AggA[chunk * NCHAN + c] = A;
  AggV[chunk * NCHAN + c] = V;
}

// mid: sequential combine across chunk aggregates per channel
__global__ void scan_mid(const float* __restrict__ AggA, const float* __restrict__ AggV,
                         float* __restrict__ Start)
{
  int c = blockIdx.x * blockDim.x + threadIdx.x;
  float h = 0.f;
#pragma unroll
  for (int j = 0; j < NCHUNK; ++j) {
    Start[j * NCHAN + c] = h;
    h = fmaf(AggA[j * NCHAN + c], h, AggV[j * NCHAN + c]);
  }
}

// pass2: replay each chunk with true carry, write h (f32)
__global__ void scan_pass2(const uint* __restrict__ Pav,
                           const float* __restrict__ Start, float* __restrict__ out)
{
  int tid = blockIdx.x * blockDim.x + threadIdx.x;
  int c = tid & (NCHAN - 1);
  int chunk = tid >> 12;
  int d = c & (D_DIM - 1);
  int b = c >> 10;
  size_t base = ((size_t)b * L_SEQ + (size_t)chunk * CH) * D_DIM + d;
  float h = Start[chunk * NCHAN + c];
#pragma unroll 4
  for (int t = 0; t < CH; ++t) {
    size_t idx = base + (size_t)t * D_DIM;
    uint u = Pav[idx];
    float a = b2f((ushort)(u & 0xFFFFu));
    float v = b2f((ushort)(u >> 16));
    h = fmaf(a, h, v);
    out[idx] = h;
  }
}

extern "C" void kernel_launch(void* const* d_in, const int* in_sizes, int n_in,
                              void* d_out, int out_size, void* d_ws, size_t ws_size,
                              hipStream_t stream) {
  (void)in_sizes; (void)n_in; (void)out_size; (void)ws_size;
  const float* x  = (const float*)d_in[0];
  const float* Wf = (const float*)d_in[1];
  const float* bf = (const float*)d_in[2];
  const float* Wi = (const float*)d_in[3];
  const float* bi = (const float*)d_in[4];
  const float* Wh = (const float*)d_in[5];
  const float* bh = (const float*)d_in[6];
  float* out = (float*)d_out;

  // workspace (~107 MB)
  ushort* xb  = (ushort*)d_ws;                         // 33.5 MB
  ushort* wfb = xb  + (size_t)M_TOTAL * K_DIM;
  ushort* wib = wfb + (size_t)N_DIM * K_DIM;
  ushort* whb = wib + (size_t)N_DIM * K_DIM;
  uint*  Pav  = (uint*)(whb + (size_t)N_DIM * K_DIM);  // 67 MB packed (a,v)
  float* AggA  = (float*)(Pav + (size_t)M_TOTAL * N_DIM);
  float* AggV  = AggA + NCHAN * NCHUNK;
  float* Start = AggV + NCHAN * NCHUNK;

  cast_f32_bf16<<<(M_TOTAL * K_DIM / 4) / 256, 256, 0, stream>>>(x,  xb,  M_TOTAL * K_DIM / 4);
  cast_f32_bf16<<<(N_DIM  * K_DIM / 4) / 256, 256, 0, stream>>>(Wf, wfb, N_DIM * K_DIM / 4);
  cast_f32_bf16<<<(N_DIM  * K_DIM / 4) / 256, 256, 0, stream>>>(Wi, wib, N_DIM * K_DIM / 4);
  cast_f32_bf16<<<(N_DIM  * K_DIM / 4) / 256, 256, 0, stream>>>(Wh, whb, N_DIM * K_DIM / 4);

  gemm_fused<<<dim3(N_DIM / BN, M_TOTAL / BM), TPB, 0, stream>>>(
      xb, wfb, wib, whb, bf, bi, bh, Pav);

  scan_pass1<<<(NCHAN * NCHUNK) / 256, 256, 0, stream>>>(Pav, AggA, AggV);
  scan_mid<<<NCHAN / 256, 256, 0, stream>>>(AggA, AggV, Start);
  scan_pass2<<<(NCHAN * NCHUNK) / 256, 256, 0, stream>>>(Pav, Start, out);
}

// Round 3
// 206.880 us; speedup vs baseline: 1.3524x; 1.0252x over previous
//
#include <hip/hip_runtime.h>

// ---- problem geometry ----
#define M_TOTAL 16384          // B*L
#define N_DIM   1024           // D
#define K_DIM   1024
#define L_SEQ   4096
#define B_SZ    4
#define D_DIM   1024
#define CH      64             // scan chunk length
#define NCHUNK  (L_SEQ / CH)   // 64
#define NCHAN   (B_SZ * D_DIM) // 4096

// ---- GEMM tile ----
#define BM 128
#define BN 128
#define BK 32
#define NK (K_DIM / BK)        // 32
#define TPB 512                // 8 waves: 2M x 4N, wave tile 64x32

typedef __attribute__((ext_vector_type(8))) short v8s;
typedef __attribute__((ext_vector_type(4))) float f32x4;

#define SB0()   __builtin_amdgcn_sched_barrier(0)
#define BAR()   __builtin_amdgcn_s_barrier()
#define WAITL0() do { asm volatile("s_waitcnt lgkmcnt(0)" ::: "memory"); SB0(); } while (0)
#define WAITV4() do { asm volatile("s_waitcnt vmcnt(4)"   ::: "memory"); SB0(); } while (0)
#define WAITV0() do { asm volatile("s_waitcnt vmcnt(0)"   ::: "memory"); SB0(); } while (0)

__device__ __forceinline__ ushort f2b(float f) {
  uint u = __float_as_uint(f);
  u += 0x7FFFu + ((u >> 16) & 1u);   // RNE (finite inputs)
  return (ushort)(u >> 16);
}
__device__ __forceinline__ float b2f(ushort u) {
  return __uint_as_float(((uint)u) << 16);
}

__global__ void cast_f32_bf16(const float* __restrict__ src, ushort* __restrict__ dst, int n4) {
  int i = blockIdx.x * blockDim.x + threadIdx.x;
  if (i >= n4) return;
  float4 v = reinterpret_cast<const float4*>(src)[i];
  ushort4 o = make_ushort4(f2b(v.x), f2b(v.y), f2b(v.z), f2b(v.w));
  reinterpret_cast<ushort4*>(dst)[i] = o;
}

// gates: f = (1+e^-ip)/(2+e^-fp+e^-ip), i = 1-f, h~ = hp>=0 ? hp+0.5 : sigmoid(hp)
__device__ __forceinline__ void gates(float fp, float ip, float hp, float& a, float& v) {
  float Ef = __expf(-fp);
  float Ei = __expf(-ip);
  float r  = __builtin_amdgcn_rcpf(2.f + Ef + Ei);
  float f  = (1.f + Ei) * r;
  float i  = (1.f + Ef) * r;
  float ht = (hp >= 0.f) ? (hp + 0.5f) : __builtin_amdgcn_rcpf(1.f + __expf(-hp));
  a = f;
  v = i * ht;
}

// Fused 3-GEMM, pipelined: 3 LDS buffers, depth-2 prefetch, counted vmcnt,
// XOR-swizzled LDS (inverse-swizzled global source, swizzled ds_read),
// 3 phases/K-tile (one per gate) with setprio'd 8-MFMA clusters.
__launch_bounds__(TPB, 2)
__global__ void gemm_fused(const ushort* __restrict__ X,
                           const ushort* __restrict__ W0, const ushort* __restrict__ W1,
                           const ushort* __restrict__ W2,
                           const float* __restrict__ bfp, const float* __restrict__ bip,
                           const float* __restrict__ bhp,
                           uint* __restrict__ Pav)
{
  __shared__ ushort lds[3][4][BM * BK];   // [buf][A,Bf,Bi,Bh]  3 x 32 KiB = 96 KiB

  // XCD-aware block swizzle (1024 blocks, 8 XCDs, bijective)
  const int id = blockIdx.x;
  const int sw = (id & 7) * 128 + (id >> 3);
  const int n0 = (sw & 7) * BN;
  const int m0 = (sw >> 3) * BM;

  const int tid  = threadIdx.x;
  const int lane = tid & 63;
  const int w    = tid >> 6;          // 0..7
  const int wr   = w >> 2;            // 0..1 : 64-row strip
  const int wc   = w & 3;             // 0..3 : 32-col strip
  const int fr   = lane & 15, g = lane >> 4;

  // ---- swizzled read offsets (halfwords). byte ^= ((row>>1)&3)<<4 ----
  int aoffh[4], boffh[2];
#pragma unroll
  for (int t = 0; t < 4; ++t) {
    int row = wr * 64 + t * 16 + fr;
    aoffh[t] = row * BK + ((g ^ ((row >> 1) & 3)) << 3);
  }
#pragma unroll
  for (int n = 0; n < 2; ++n) {
    int row = wc * 32 + n * 16 + fr;
    boffh[n] = row * BK + ((g ^ ((row >> 1) & 3)) << 3);
  }

  // ---- staging: thread -> one 16B slot per matrix; inverse-swizzled source ----
  const int srow = tid >> 2;                       // 0..127
  const int k16s = (tid & 3) ^ ((srow >> 1) & 3);  // involution
  const ushort* sA  = X  + (size_t)(m0 + srow) * K_DIM + k16s * 8;
  const ushort* sB0 = W0 + (size_t)(n0 + srow) * K_DIM + k16s * 8;
  const ushort* sB1 = W1 + (size_t)(n0 + srow) * K_DIM + k16s * 8;
  const ushort* sB2 = W2 + (size_t)(n0 + srow) * K_DIM + k16s * 8;
  const int dslot = tid * 8;                       // halfword dest slot

  auto issue = [&](int buf, int mat, const ushort* src, int kt) {
    __builtin_amdgcn_global_load_lds(
        (const __attribute__((address_space(1))) void*)(src + kt * BK),
        (__attribute__((address_space(3))) void*)(&lds[buf][mat][dslot]), 16, 0, 0);
  };

  f32x4 acc[3][4][2] = {};

  // prologue: stage tiles 0 and 1 fully (4 loads each, fixed order)
  issue(0, 0, sA, 0); issue(0, 1, sB0, 0); issue(0, 2, sB1, 0); issue(0, 3, sB2, 0);
  issue(1, 0, sA, 1); issue(1, 1, sB0, 1); issue(1, 2, sB1, 1); issue(1, 3, sB2, 1);
  WAITV4();           // tile 0 landed; tile 1 may be in flight
  BAR(); SB0();

  int bc = 0, bn = 2; // current buf, staging target buf
  for (int t = 0; t < NK; ++t) {
    const ushort* rb = &lds[bc][0][0];
    const bool st = (t + 2 < NK);
    v8s af[4], b0, b1;

    // ---- phase z=0 ----
#pragma unroll
    for (int q = 0; q < 4; ++q) af[q] = *reinterpret_cast<const v8s*>(rb + aoffh[q]);
    b0 = *reinterpret_cast<const v8s*>(rb + 1 * BM * BK + boffh[0]);
    b1 = *reinterpret_cast<const v8s*>(rb + 1 * BM * BK + boffh[1]);
    if (st) { issue(bn, 0, sA, t + 2); issue(bn, 1, sB0, t + 2); }
    SB0(); BAR(); WAITL0();
    __builtin_amdgcn_s_setprio(1);
#pragma unroll
    for (int mi = 0; mi < 4; ++mi) {
      acc[0][mi][0] = __builtin_amdgcn_mfma_f32_16x16x32_bf16(af[mi], b0, acc[0][mi][0], 0, 0, 0);
      acc[0][mi][1] = __builtin_amdgcn_mfma_f32_16x16x32_bf16(af[mi], b1, acc[0][mi][1], 0, 0, 0);
    }
    __builtin_amdgcn_s_setprio(0);

    // ---- phase z=1 ----
    b0 = *reinterpret_cast<const v8s*>(rb + 2 * BM * BK + boffh[0]);
    b1 = *reinterpret_cast<const v8s*>(rb + 2 * BM * BK + boffh[1]);
    if (st) issue(bn, 2, sB1, t + 2);
    SB0(); BAR(); WAITL0();
    __builtin_amdgcn_s_setprio(1);
#pragma unroll
    for (int mi = 0; mi < 4; ++mi) {
      acc[1][mi][0] = __builtin_amdgcn_mfma_f32_16x16x32_bf16(af[mi], b0, acc[1][mi][0], 0, 0, 0);
      acc[1][mi][1] = __builtin_amdgcn_mfma_f32_16x16x32_bf16(af[mi], b1, acc[1][mi][1], 0, 0, 0);
    }
    __builtin_amdgcn_s_setprio(0);

    // ---- phase z=2 ----
    b0 = *reinterpret_cast<const v8s*>(rb + 3 * BM * BK + boffh[0]);
    b1 = *reinterpret_cast<const v8s*>(rb + 3 * BM * BK + boffh[1]);
    if (st) issue(bn, 3, sB2, t + 2);
    SB0(); BAR(); WAITL0();
    __builtin_amdgcn_s_setprio(1);
#pragma unroll
    for (int mi = 0; mi < 4; ++mi) {
      acc[2][mi][0] = __builtin_amdgcn_mfma_f32_16x16x32_bf16(af[mi], b0, acc[2][mi][0], 0, 0, 0);
      acc[2][mi][1] = __builtin_amdgcn_mfma_f32_16x16x32_bf16(af[mi], b1, acc[2][mi][1], 0, 0, 0);
    }
    __builtin_amdgcn_s_setprio(0);

    // ---- tile boundary: wait for next tile's stage (keep t+2's 4 loads in flight) ----
    if (t < NK - 2) { WAITV4(); } else { WAITV0(); }
    SB0(); BAR(); SB0();

    bc = (bc == 2) ? 0 : bc + 1;
    bn = (bn == 2) ? 0 : bn + 1;
  }

  // epilogue: C/D layout col=lane&15, row=(lane>>4)*4+r  [m89-verified]
#pragma unroll
  for (int ni = 0; ni < 2; ++ni) {
    const int col = n0 + wc * 32 + ni * 16 + fr;
    const float vbf = bfp[col], vbi = bip[col], vbh = bhp[col];
#pragma unroll
    for (int mi = 0; mi < 4; ++mi) {
      const int row0 = m0 + wr * 64 + mi * 16 + g * 4;
#pragma unroll
      for (int r = 0; r < 4; ++r) {
        float a, v;
        gates(acc[0][mi][ni][r] + vbf, acc[1][mi][ni][r] + vbi, acc[2][mi][ni][r] + vbh, a, v);
        Pav[(size_t)(row0 + r) * N_DIM + col] = (uint)f2b(a) | ((uint)f2b(v) << 16);
      }
    }
  }
}

// pass1: per (channel, chunk) aggregate: h_end = A*h_start + V
__global__ void scan_pass1(const uint* __restrict__ Pav,
                           float* __restrict__ AggA, float* __restrict__ AggV)
{
  int tid = blockIdx.x * blockDim.x + threadIdx.x;
  int c = tid & (NCHAN - 1);
  int chunk = tid >> 12;
  int d = c & (D_DIM - 1);
  int b = c >> 10;
  size_t base = ((size_t)b * L_SEQ + (size_t)chunk * CH) * D_DIM + d;
  float A = 1.f, V = 0.f;
#pragma unroll 4
  for (int t = 0; t < CH; ++t) {
    uint u = Pav[base + (size_t)t * D_DIM];
    float a = b2f((ushort)(u & 0xFFFFu));
    float v = b2f((ushort)(u >> 16));
    A *= a;
    V = fmaf(a, V, v);
  }
  AggA[chunk * NCHAN + c] = A;
  AggV[chunk * NCHAN + c] = V;
}

// mid: sequential combine across chunk aggregates per channel
__global__ void scan_mid(const float* __restrict__ AggA, const float* __restrict__ AggV,
                         float* __restrict__ Start)
{
  int c = blockIdx.x * blockDim.x + threadIdx.x;
  float h = 0.f;
#pragma unroll
  for (int j = 0; j < NCHUNK; ++j) {
    Start[j * NCHAN + c] = h;
    h = fmaf(AggA[j * NCHAN + c], h, AggV[j * NCHAN + c]);
  }
}

// pass2: replay each chunk with true carry, write h (f32)
__global__ void scan_pass2(const uint* __restrict__ Pav,
                           const float* __restrict__ Start, float* __restrict__ out)
{
  int tid = blockIdx.x * blockDim.x + threadIdx.x;
  int c = tid & (NCHAN - 1);
  int chunk = tid >> 12;
  int d = c & (D_DIM - 1);
  int b = c >> 10;
  size_t base = ((size_t)b * L_SEQ + (size_t)chunk * CH) * D_DIM + d;
  float h = Start[chunk * NCHAN + c];
#pragma unroll 4
  for (int t = 0; t < CH; ++t) {
    size_t idx = base + (size_t)t * D_DIM;
    uint u = Pav[idx];
    float a = b2f((ushort)(u & 0xFFFFu));
    float v = b2f((ushort)(u >> 16));
    h = fmaf(a, h, v);
    out[idx] = h;
  }
}

extern "C" void kernel_launch(void* const* d_in, const int* in_sizes, int n_in,
                              void* d_out, int out_size, void* d_ws, size_t ws_size,
                              hipStream_t stream) {
  (void)in_sizes; (void)n_in; (void)out_size; (void)ws_size;
  const float* x  = (const float*)d_in[0];
  const float* Wf = (const float*)d_in[1];
  const float* bf = (const float*)d_in[2];
  const float* Wi = (const float*)d_in[3];
  const float* bi = (const float*)d_in[4];
  const float* Wh = (const float*)d_in[5];
  const float* bh = (const float*)d_in[6];
  float* out = (float*)d_out;

  // workspace (~107 MB)
  ushort* xb  = (ushort*)d_ws;                         // 33.5 MB
  ushort* wfb = xb  + (size_t)M_TOTAL * K_DIM;
  ushort* wib = wfb + (size_t)N_DIM * K_DIM;
  ushort* whb = wib + (size_t)N_DIM * K_DIM;
  uint*  Pav  = (uint*)(whb + (size_t)N_DIM * K_DIM);  // 67 MB packed (a,v)
  float* AggA  = (float*)(Pav + (size_t)M_TOTAL * N_DIM);
  float* AggV  = AggA + NCHAN * NCHUNK;
  float* Start = AggV + NCHAN * NCHUNK;

  cast_f32_bf16<<<(M_TOTAL * K_DIM / 4) / 256, 256, 0, stream>>>(x,  xb,  M_TOTAL * K_DIM / 4);
  cast_f32_bf16<<<(N_DIM  * K_DIM / 4) / 256, 256, 0, stream>>>(Wf, wfb, N_DIM * K_DIM / 4);
  cast_f32_bf16<<<(N_DIM  * K_DIM / 4) / 256, 256, 0, stream>>>(Wi, wib, N_DIM * K_DIM / 4);
  cast_f32_bf16<<<(N_DIM  * K_DIM / 4) / 256, 256, 0, stream>>>(Wh, whb, N_DIM * K_DIM / 4);

  gemm_fused<<<dim3((M_TOTAL / BM) * (N_DIM / BN)), TPB, 0, stream>>>(
      xb, wfb, wib, whb, bf, bi, bh, Pav);

  scan_pass1<<<(NCHAN * NCHUNK) / 256, 256, 0, stream>>>(Pav, AggA, AggV);
  scan_mid<<<NCHAN / 256, 256, 0, stream>>>(AggA, AggV, Start);
  scan_pass2<<<(NCHAN * NCHUNK) / 256, 256, 0, stream>>>(Pav, Start, out);
}

// Round 4
// 188.775 us; speedup vs baseline: 1.4821x; 1.0959x over previous
//
#include <hip/hip_runtime.h>

// ---- problem geometry ----
#define M_TOTAL 16384          // B*L
#define N_DIM   1024           // D
#define K_DIM   1024
#define L_SEQ   4096
#define B_SZ    4
#define D_DIM   1024
#define CH      64             // scan chunk length
#define NCHUNK  (L_SEQ / CH)   // 64
#define NCHAN   (B_SZ * D_DIM) // 4096

// ---- GEMM tile ----
#define BM 128
#define BN 128
#define BK 64
#define NKT (K_DIM / BK)       // 16
#define TPB 512                // 8 waves: 2M x 4N, wave tile 64x32

typedef __attribute__((ext_vector_type(8))) short v8s;
typedef __attribute__((ext_vector_type(4))) float f32x4;

#define SB0()   __builtin_amdgcn_sched_barrier(0)
#define BAR()   __builtin_amdgcn_s_barrier()
#define WAITL0() do { asm volatile("s_waitcnt lgkmcnt(0)" ::: "memory"); SB0(); } while (0)
#define WAITV6() do { asm volatile("s_waitcnt vmcnt(6)"   ::: "memory"); SB0(); } while (0)
#define WAITV4() do { asm volatile("s_waitcnt vmcnt(4)"   ::: "memory"); SB0(); } while (0)
#define WAITV0() do { asm volatile("s_waitcnt vmcnt(0)"   ::: "memory"); SB0(); } while (0)
#define AS1 __attribute__((address_space(1)))
#define AS3 __attribute__((address_space(3)))

__device__ __forceinline__ ushort f2b(float f) {
  uint u = __float_as_uint(f);
  u += 0x7FFFu + ((u >> 16) & 1u);   // RNE (finite inputs)
  return (ushort)(u >> 16);
}
__device__ __forceinline__ float b2f(ushort u) {
  return __uint_as_float(((uint)u) << 16);
}

__global__ void cast_f32_bf16(const float* __restrict__ src, ushort* __restrict__ dst, int n4) {
  int i = blockIdx.x * blockDim.x + threadIdx.x;
  if (i >= n4) return;
  float4 v = reinterpret_cast<const float4*>(src)[i];
  ushort4 o = make_ushort4(f2b(v.x), f2b(v.y), f2b(v.z), f2b(v.w));
  reinterpret_cast<ushort4*>(dst)[i] = o;
}

// gates: f = (1+e^-ip)/(2+e^-fp+e^-ip), i = 1-f, h~ = hp>=0 ? hp+0.5 : sigmoid(hp)
__device__ __forceinline__ void gates(float fp, float ip, float hp, float& a, float& v) {
  float Ef = __expf(-fp);
  float Ei = __expf(-ip);
  float r  = __builtin_amdgcn_rcpf(2.f + Ef + Ei);
  float f  = (1.f + Ei) * r;
  float i  = (1.f + Ef) * r;
  float ht = (hp >= 0.f) ? (hp + 0.5f) : __builtin_amdgcn_rcpf(1.f + __expf(-hp));
  a = f;
  v = i * ht;
}

// Fused 3-GEMM: BK=64, 2 LDS dbuf, 3 phases/K-tile (one gate each, 16-MFMA clusters),
// staggered counted vmcnt (4/6/6), XOR-swizzled LDS, setprio'd MFMA.
__launch_bounds__(TPB, 2)
__global__ void gemm_fused(const ushort* __restrict__ X,
                           const ushort* __restrict__ W0, const ushort* __restrict__ W1,
                           const ushort* __restrict__ W2,
                           const float* __restrict__ bfp, const float* __restrict__ bip,
                           const float* __restrict__ bhp,
                           uint* __restrict__ Pav)
{
  __shared__ ushort lds[2][4][BM * BK];   // [buf][A,Bf,Bi,Bh]  2 x 64 KiB = 128 KiB

  // XCD-aware block swizzle (1024 blocks, 8 XCDs, bijective)
  const int id = blockIdx.x;
  const int sw = (id & 7) * 128 + (id >> 3);
  const int n0 = (sw & 7) * BN;
  const int m0 = (sw >> 3) * BM;

  const int tid  = threadIdx.x;
  const int lane = tid & 63;
  const int w    = tid >> 6;          // 0..7
  const int wr   = w >> 2;            // 0..1 : 64-row strip
  const int wc   = w & 3;             // 0..3 : 32-col strip
  const int fr   = lane & 15, g = lane >> 4;

  // ---- swizzled ds_read offsets (halfwords): slot k16 = ks*4+g, swizzled by row&7 (== fr&7) ----
  int aoffh[4][2], boffh[2][2];
#pragma unroll
  for (int q = 0; q < 4; ++q)
#pragma unroll
    for (int ks = 0; ks < 2; ++ks) {
      int row = wr * 64 + q * 16 + fr;
      aoffh[q][ks] = row * BK + (((ks * 4 + g) ^ (row & 7)) << 3);
    }
#pragma unroll
  for (int n = 0; n < 2; ++n)
#pragma unroll
    for (int ks = 0; ks < 2; ++ks) {
      int row = wc * 32 + n * 16 + fr;
      boffh[n][ks] = row * BK + (((ks * 4 + g) ^ (row & 7)) << 3);
    }

  // ---- staging: 2 x 16B slots per matrix per thread; inverse-swizzled global source ----
  const int s0 = tid, s1 = 512 + tid;
  const int r0 = s0 >> 3, k0 = (s0 & 7) ^ (r0 & 7);
  const int r1 = s1 >> 3, k1 = (s1 & 7) ^ (r1 & 7);
  const int d0 = s0 * 8, d1 = s1 * 8;   // halfword dest offsets

  const ushort* gsrc[4][2];
  gsrc[0][0] = X  + (size_t)(m0 + r0) * K_DIM + k0 * 8;
  gsrc[0][1] = X  + (size_t)(m0 + r1) * K_DIM + k1 * 8;
  gsrc[1][0] = W0 + (size_t)(n0 + r0) * K_DIM + k0 * 8;
  gsrc[1][1] = W0 + (size_t)(n0 + r1) * K_DIM + k1 * 8;
  gsrc[2][0] = W1 + (size_t)(n0 + r0) * K_DIM + k0 * 8;
  gsrc[2][1] = W1 + (size_t)(n0 + r1) * K_DIM + k1 * 8;
  gsrc[3][0] = W2 + (size_t)(n0 + r0) * K_DIM + k0 * 8;
  gsrc[3][1] = W2 + (size_t)(n0 + r1) * K_DIM + k1 * 8;

  auto issue = [&](int buf, int mat, int kt, int j) {
    const ushort* s_ = gsrc[mat][j] + kt * BK;
    __builtin_amdgcn_global_load_lds((const AS1 void*)s_,
        (AS3 void*)(&lds[buf][mat][j ? d1 : d0]), 16, 0, 0);
  };

  f32x4 acc[3][4][2] = {};

  // prologue: stage tile 0 (order A,B0,B1,B2 -> oldest-first matches wait ladder)
#pragma unroll
  for (int mat = 0; mat < 4; ++mat) { issue(0, mat, 0, 0); issue(0, mat, 0, 1); }
  WAITV4();    // A,B0 landed; B1,B2 may fly
  BAR(); SB0();

  int cur = 0;
  for (int t = 0; t < NKT; ++t) {
    const bool pf = (t + 1 < NKT);
    const ushort* rb = &lds[cur][0][0];
    v8s aF[4][2], bF[2][2];

    // ---- phase 0: gate f (reads A + B0; issues next A,B0) ----
#pragma unroll
    for (int q = 0; q < 4; ++q)
#pragma unroll
      for (int ks = 0; ks < 2; ++ks)
        aF[q][ks] = *reinterpret_cast<const v8s*>(rb + aoffh[q][ks]);
#pragma unroll
    for (int n = 0; n < 2; ++n)
#pragma unroll
      for (int ks = 0; ks < 2; ++ks)
        bF[n][ks] = *reinterpret_cast<const v8s*>(rb + 1 * BM * BK + boffh[n][ks]);
    if (pf) { issue(cur ^ 1, 0, t + 1, 0); issue(cur ^ 1, 0, t + 1, 1);
              issue(cur ^ 1, 1, t + 1, 0); issue(cur ^ 1, 1, t + 1, 1); }
    SB0(); WAITL0();
    __builtin_amdgcn_s_setprio(1);
#pragma unroll
    for (int ks = 0; ks < 2; ++ks)
#pragma unroll
      for (int mi = 0; mi < 4; ++mi) {
        acc[0][mi][0] = __builtin_amdgcn_mfma_f32_16x16x32_bf16(aF[mi][ks], bF[0][ks], acc[0][mi][0], 0, 0, 0);
        acc[0][mi][1] = __builtin_amdgcn_mfma_f32_16x16x32_bf16(aF[mi][ks], bF[1][ks], acc[0][mi][1], 0, 0, 0);
      }
    __builtin_amdgcn_s_setprio(0);
    WAITV6(); BAR(); SB0();   // B1 of tile t landed

    // ---- phase 1: gate i ----
#pragma unroll
    for (int n = 0; n < 2; ++n)
#pragma unroll
      for (int ks = 0; ks < 2; ++ks)
        bF[n][ks] = *reinterpret_cast<const v8s*>(rb + 2 * BM * BK + boffh[n][ks]);
    if (pf) { issue(cur ^ 1, 2, t + 1, 0); issue(cur ^ 1, 2, t + 1, 1); }
    SB0(); WAITL0();
    __builtin_amdgcn_s_setprio(1);
#pragma unroll
    for (int ks = 0; ks < 2; ++ks)
#pragma unroll
      for (int mi = 0; mi < 4; ++mi) {
        acc[1][mi][0] = __builtin_amdgcn_mfma_f32_16x16x32_bf16(aF[mi][ks], bF[0][ks], acc[1][mi][0], 0, 0, 0);
        acc[1][mi][1] = __builtin_amdgcn_mfma_f32_16x16x32_bf16(aF[mi][ks], bF[1][ks], acc[1][mi][1], 0, 0, 0);
      }
    __builtin_amdgcn_s_setprio(0);
    WAITV6(); BAR(); SB0();   // B2 of tile t landed

    // ---- phase 2: gate h ----
#pragma unroll
    for (int n = 0; n < 2; ++n)
#pragma unroll
      for (int ks = 0; ks < 2; ++ks)
        bF[n][ks] = *reinterpret_cast<const v8s*>(rb + 3 * BM * BK + boffh[n][ks]);
    if (pf) { issue(cur ^ 1, 3, t + 1, 0); issue(cur ^ 1, 3, t + 1, 1); }
    SB0(); WAITL0();
    __builtin_amdgcn_s_setprio(1);
#pragma unroll
    for (int ks = 0; ks < 2; ++ks)
#pragma unroll
      for (int mi = 0; mi < 4; ++mi) {
        acc[2][mi][0] = __builtin_amdgcn_mfma_f32_16x16x32_bf16(aF[mi][ks], bF[0][ks], acc[2][mi][0], 0, 0, 0);
        acc[2][mi][1] = __builtin_amdgcn_mfma_f32_16x16x32_bf16(aF[mi][ks], bF[1][ks], acc[2][mi][1], 0, 0, 0);
      }
    __builtin_amdgcn_s_setprio(0);

    // ---- tile boundary ----
    if (pf) {
      if (t + 2 == NKT) { WAITV0(); } else { WAITV4(); }  // next tile's A,B0 landed (drain before final tile)
      BAR(); SB0();
      cur ^= 1;
    }
  }

  // epilogue: C/D layout col=lane&15, row=(lane>>4)*4+r  [m89-verified]
#pragma unroll
  for (int ni = 0; ni < 2; ++ni) {
    const int col = n0 + wc * 32 + ni * 16 + fr;
    const float vbf = bfp[col], vbi = bip[col], vbh = bhp[col];
#pragma unroll
    for (int mi = 0; mi < 4; ++mi) {
      const int row0 = m0 + wr * 64 + mi * 16 + g * 4;
#pragma unroll
      for (int r = 0; r < 4; ++r) {
        float a, v;
        gates(acc[0][mi][ni][r] + vbf, acc[1][mi][ni][r] + vbi, acc[2][mi][ni][r] + vbh, a, v);
        Pav[(size_t)(row0 + r) * N_DIM + col] = (uint)f2b(a) | ((uint)f2b(v) << 16);
      }
    }
  }
}

// pass1: per (channel, chunk) aggregate: h_end = A*h_start + V
__global__ void scan_pass1(const uint* __restrict__ Pav,
                           float* __restrict__ AggA, float* __restrict__ AggV)
{
  int tid = blockIdx.x * blockDim.x + threadIdx.x;
  int c = tid & (NCHAN - 1);
  int chunk = tid >> 12;
  int d = c & (D_DIM - 1);
  int b = c >> 10;
  size_t base = ((size_t)b * L_SEQ + (size_t)chunk * CH) * D_DIM + d;
  float A = 1.f, V = 0.f;
#pragma unroll 4
  for (int t = 0; t < CH; ++t) {
    uint u = Pav[base + (size_t)t * D_DIM];
    float a = b2f((ushort)(u & 0xFFFFu));
    float v = b2f((ushort)(u >> 16));
    A *= a;
    V = fmaf(a, V, v);
  }
  AggA[chunk * NCHAN + c] = A;
  AggV[chunk * NCHAN + c] = V;
}

// mid: sequential combine across chunk aggregates per channel
__global__ void scan_mid(const float* __restrict__ AggA, const float* __restrict__ AggV,
                         float* __restrict__ Start)
{
  int c = blockIdx.x * blockDim.x + threadIdx.x;
  float h = 0.f;
#pragma unroll
  for (int j = 0; j < NCHUNK; ++j) {
    Start[j * NCHAN + c] = h;
    h = fmaf(AggA[j * NCHAN + c], h, AggV[j * NCHAN + c]);
  }
}

// pass2: replay each chunk with true carry, write h (f32)
__global__ void scan_pass2(const uint* __restrict__ Pav,
                           const float* __restrict__ Start, float* __restrict__ out)
{
  int tid = blockIdx.x * blockDim.x + threadIdx.x;
  int c = tid & (NCHAN - 1);
  int chunk = tid >> 12;
  int d = c & (D_DIM - 1);
  int b = c >> 10;
  size_t base = ((size_t)b * L_SEQ + (size_t)chunk * CH) * D_DIM + d;
  float h = Start[chunk * NCHAN + c];
#pragma unroll 4
  for (int t = 0; t < CH; ++t) {
    size_t idx = base + (size_t)t * D_DIM;
    uint u = Pav[idx];
    float a = b2f((ushort)(u & 0xFFFFu));
    float v = b2f((ushort)(u >> 16));
    h = fmaf(a, h, v);
    out[idx] = h;
  }
}

extern "C" void kernel_launch(void* const* d_in, const int* in_sizes, int n_in,
                              void* d_out, int out_size, void* d_ws, size_t ws_size,
                              hipStream_t stream) {
  (void)in_sizes; (void)n_in; (void)out_size; (void)ws_size;
  const float* x  = (const float*)d_in[0];
  const float* Wf = (const float*)d_in[1];
  const float* bf = (const float*)d_in[2];
  const float* Wi = (const float*)d_in[3];
  const float* bi = (const float*)d_in[4];
  const float* Wh = (const float*)d_in[5];
  const float* bh = (const float*)d_in[6];
  float* out = (float*)d_out;

  // workspace (~107 MB)
  ushort* xb  = (ushort*)d_ws;                         // 33.5 MB
  ushort* wfb = xb  + (size_t)M_TOTAL * K_DIM;
  ushort* wib = wfb + (size_t)N_DIM * K_DIM;
  ushort* whb = wib + (size_t)N_DIM * K_DIM;
  uint*  Pav  = (uint*)(whb + (size_t)N_DIM * K_DIM);  // 67 MB packed (a,v)
  float* AggA  = (float*)(Pav + (size_t)M_TOTAL * N_DIM);
  float* AggV  = AggA + NCHAN * NCHUNK;
  float* Start = AggV + NCHAN * NCHUNK;

  cast_f32_bf16<<<(M_TOTAL * K_DIM / 4) / 256, 256, 0, stream>>>(x,  xb,  M_TOTAL * K_DIM / 4);
  cast_f32_bf16<<<(N_DIM  * K_DIM / 4) / 256, 256, 0, stream>>>(Wf, wfb, N_DIM * K_DIM / 4);
  cast_f32_bf16<<<(N_DIM  * K_DIM / 4) / 256, 256, 0, stream>>>(Wi, wib, N_DIM * K_DIM / 4);
  cast_f32_bf16<<<(N_DIM  * K_DIM / 4) / 256, 256, 0, stream>>>(Wh, whb, N_DIM * K_DIM / 4);

  gemm_fused<<<dim3((M_TOTAL / BM) * (N_DIM / BN)), TPB, 0, stream>>>(
      xb, wfb, wib, whb, bf, bi, bh, Pav);

  scan_pass1<<<(NCHAN * NCHUNK) / 256, 256, 0, stream>>>(Pav, AggA, AggV);
  scan_mid<<<NCHAN / 256, 256, 0, stream>>>(AggA, AggV, Start);
  scan_pass2<<<(NCHAN * NCHUNK) / 256, 256, 0, stream>>>(Pav, Start, out);
}